// Round 14
// baseline (139.348 us; speedup 1.0000x reference)
//
#include <hip/hip_runtime.h>
#include <stdint.h>

#define D_MODEL 1024
#define SEQ 2048
#define HALF 1024
#define K_EIG 24
#define GUARD4 24              // zero 16B-elements (8 rows each) before each slice = 192 rows
#define K4 128                 // real elements per slice (1024 rows / 8)
#define K4P (GUARD4 + K4)      // 152
#define WE_JP4 72              // 64 real + 8 zero (stage overrun)

typedef __attribute__((ext_vector_type(8))) short bf16x8;
typedef __attribute__((ext_vector_type(4))) float f32x4;
typedef _Float16 f16;
typedef _Float16 f16x2 __attribute__((ext_vector_type(2)));
typedef unsigned int uint;

#define GAS __attribute__((address_space(1)))
#define LAS __attribute__((address_space(3)))

static __device__ __forceinline__ unsigned short f2bf(float f) {
  union { float f; uint32_t u; } v; v.f = f;
  uint32_t u = v.u;
  u += 0x7FFFu + ((u >> 16) & 1u);
  return (unsigned short)(u >> 16);
}

static __device__ __forceinline__ float dot2(uint w2, uint u2, float c) {
  return __builtin_amdgcn_fdot2(__builtin_bit_cast(f16x2, w2),
                                __builtin_bit_cast(f16x2, u2), c, false);
}

static __device__ __forceinline__ uint pkrtz(float lo, float hi) {
  return __builtin_bit_cast(uint, __builtin_amdgcn_cvt_pkrtz(lo, hi));
}

static __device__ __forceinline__ uint pkbf(float lo, float hi) {
  return (uint)f2bf(lo) | ((uint)f2bf(hi) << 16);
}

// ---------------- zero the per-slice guard elements of u4 ----------------
__global__ void k_zero_guard(uint4* __restrict__ u4) {
  int idx = blockIdx.x * 256 + threadIdx.x;   // grid (96,8): 24576 uint4 per slice guard
  int r = blockIdx.y;
  u4[(size_t)r * (K4P * 1024) + idx] = make_uint4(0u, 0u, 0u, 0u);
}

// ------------- M_inputs [K][N] fp32 -> Mt [N][K] bf16 -------------
__global__ void k_transpose_M(const float* __restrict__ M, unsigned short* __restrict__ Mt) {
  __shared__ float tile[32][33];
  int k0 = blockIdx.y * 32, n0 = blockIdx.x * 32;
  int tx = threadIdx.x & 31, ty = threadIdx.x >> 5;
  #pragma unroll
  for (int r = 0; r < 32; r += 8)
    tile[ty + r][tx] = M[(size_t)(k0 + ty + r) * D_MODEL + n0 + tx];
  __syncthreads();
  #pragma unroll
  for (int r = 0; r < 32; r += 8)
    Mt[(size_t)(n0 + ty + r) * D_MODEL + k0 + tx] = f2bf(tile[tx][ty + r]);
}

// ------------- we4[jp4][d] = 16B of 8 even-taps: dword q = (w_e[8jp4+2q], w_e[8jp4+2q+1]) f16 -------------
__global__ __launch_bounds__(256) void k_we4(const float* __restrict__ phi,
                                             const float* __restrict__ Mf,
                                             uint4* __restrict__ we4) {
  const int jp4 = blockIdx.x;                       // 0..71
  const int d = blockIdx.y * 256 + threadIdx.x;     // 0..1023
  if (jp4 >= 64) {
    we4[(size_t)jp4 * D_MODEL + d] = make_uint4(0u, 0u, 0u, 0u);
    return;
  }
  __shared__ float ph[8][K_EIG];
  if (threadIdx.x < 8 * K_EIG) {
    int s = threadIdx.x / K_EIG, k = threadIdx.x - s * K_EIG;
    ph[s][k] = phi[(size_t)(16 * jp4 + 2 * s) * K_EIG + k];
  }
  __syncthreads();
  float s[8] = {};
  #pragma unroll
  for (int k = 0; k < K_EIG; ++k) {
    float mv = Mf[(size_t)k * D_MODEL + d];
    #pragma unroll
    for (int j = 0; j < 8; ++j) s[j] = fmaf(ph[j][k], mv, s[j]);
  }
  uint4 o;
  o.x = pkrtz(2.f * s[0], 2.f * s[1]);
  o.y = pkrtz(2.f * s[2], 2.f * s[3]);
  o.z = pkrtz(2.f * s[4], 2.f * s[5]);
  o.w = pkrtz(2.f * s[6], 2.f * s[7]);
  we4[(size_t)jp4 * D_MODEL + d] = o;
}

// ------------- u = x @ M (bf16 MFMA, B^T), A staged from fp32 x with fused cvt, pipelined -------------
__global__ __launch_bounds__(256) void k_gemm(const float* __restrict__ X,
                                              const unsigned short* __restrict__ Bt,
                                              uint* __restrict__ Ug) {
  __shared__ unsigned short As[128 * 32];
  __shared__ unsigned short Bs[128 * 32];
  const int bid = (int)blockIdx.x;             // 0..511
  const int swz = (bid & 7) * 64 + (bid >> 3);
  const int m0 = (swz >> 3) * 128;
  const int n0 = (swz & 7) * 128;
  const int tid = threadIdx.x;
  const int lane = tid & 63;
  const int wave = tid >> 6;
  const int wm = wave >> 1, wn = wave & 1;
  const int srow = lane >> 2;
  const int skoff = (lane & 3) * 8;

  const int arow = tid >> 1;
  const int akh  = (tid & 1) * 16;
  const float* xsrc = X + (size_t)(m0 + arow) * 1024 + akh;
  unsigned short* adst = As + arow * 32 + akh;

  f32x4 acc[4][4] = {};

  float4 xv0 = *(const float4*)(xsrc);
  float4 xv1 = *(const float4*)(xsrc + 4);
  float4 xv2 = *(const float4*)(xsrc + 8);
  float4 xv3 = *(const float4*)(xsrc + 12);

  for (int k0 = 0; k0 < 1024; k0 += 32) {
    __syncthreads();
    #pragma unroll
    for (int c = 0; c < 2; ++c) {
      int rbase = wave * 32 + c * 16;
      const unsigned short* src = Bt + (size_t)(n0 + rbase + srow) * 1024 + k0 + skoff;
      __builtin_amdgcn_global_load_lds((const GAS void*)src, (LAS void*)(Bs + rbase * 32), 16, 0, 0);
    }
    uint4 w0, w1;
    w0.x = pkbf(xv0.x, xv0.y); w0.y = pkbf(xv0.z, xv0.w);
    w0.z = pkbf(xv1.x, xv1.y); w0.w = pkbf(xv1.z, xv1.w);
    w1.x = pkbf(xv2.x, xv2.y); w1.y = pkbf(xv2.z, xv2.w);
    w1.z = pkbf(xv3.x, xv3.y); w1.w = pkbf(xv3.z, xv3.w);
    *(uint4*)(adst) = w0;
    *(uint4*)(adst + 8) = w1;
    __syncthreads();

    {
      const int kn = (k0 + 32) & 1023;
      xv0 = *(const float4*)(xsrc + kn);
      xv1 = *(const float4*)(xsrc + kn + 4);
      xv2 = *(const float4*)(xsrc + kn + 8);
      xv3 = *(const float4*)(xsrc + kn + 12);
    }

    bf16x8 a[4], b[4];
    #pragma unroll
    for (int mt = 0; mt < 4; ++mt)
      a[mt] = *(const bf16x8*)(As + ((wm * 64 + mt * 16 + (lane & 15)) * 32 + (lane >> 4) * 8));
    #pragma unroll
    for (int nt = 0; nt < 4; ++nt)
      b[nt] = *(const bf16x8*)(Bs + ((wn * 64 + nt * 16 + (lane & 15)) * 32 + (lane >> 4) * 8));
    #pragma unroll
    for (int mt = 0; mt < 4; ++mt)
      #pragma unroll
      for (int nt = 0; nt < 4; ++nt)
        acc[mt][nt] = __builtin_amdgcn_mfma_f32_16x16x32_bf16(a[mt], b[nt], acc[mt][nt], 0, 0, 0);
  }

  const int crow = (lane >> 4) * 4;
  const int ccol = lane & 15;
  #pragma unroll
  for (int mt = 0; mt < 4; ++mt) {
    int m = m0 + wm * 64 + mt * 16 + crow;
    int b_ = m >> 11;
    int t0 = m & 2047;
    int r_e = b_ << 1;
    int k4 = t0 >> 4;
    int dwo = (t0 >> 2) & 3;
    size_t base_e = ((size_t)(r_e * K4P + GUARD4 + k4) * 1024) * 4 + dwo;
    size_t base_o = ((size_t)((r_e + 1) * K4P + GUARD4 + k4) * 1024) * 4 + dwo;
    #pragma unroll
    for (int nt = 0; nt < 4; ++nt) {
      int n = n0 + wn * 64 + nt * 16 + ccol;
      Ug[base_e + (size_t)n * 4] = pkrtz(acc[mt][nt][0], acc[mt][nt][2]);
      Ug[base_o + (size_t)n * 4] = pkrtz(acc[mt][nt][1], acc[mt][nt][3]);
    }
  }
}

// ------------- depthwise causal conv: packed-pair ring + dot2, 32-tap chunks, 40KB LDS -------------
// 512 thr = 64 d-lanes x 8 waves, 16 outputs/thread, 4 blocks/CU (all 1024 blocks co-resident).
// Balanced mapping: r = flat&7 (pins XCD to one u-slice), k = flat>>3, a = B[k&7] with
// B = {7,0,3,4,6,1,2,5} -- aligned k-quads sum to 52 work-units each.
__global__ __launch_bounds__(512, 8) void k_conv(const uint4* __restrict__ u4,
                                                 const uint4* __restrict__ we4,
                                                 float* __restrict__ out) {
  __shared__ uint4 u_r[32 * 64];     // 32KB ring: [k4 & 31][dl], element = 4 pairs = 8 rows
  __shared__ uint4 w_s[2][4][64];    // 8KB: double-buffered 32-tap chunk (4 w-elements)
  const int flat = blockIdx.x;       // 0..1023
  const int r  = flat & 7;
  const int k_ = flat >> 3;          // 0..127
  const int a  = (int)((0x52164307u >> ((k_ & 7) * 4)) & 7u);
  const int dt = k_ >> 3;            // 0..15
  const int d0 = dt * 64;
  const int tid = threadIdx.x;
  const int dl = tid & 63;
  const int ig = tid >> 6;           // wave 0..7

  const uint4* ub = u4 + ((size_t)r * K4P + GUARD4) * 1024 + d0;   // + k4*1024 + dl
  const int b_ = r >> 1, p = r & 1;

  // stage 8 u elements [k40, k40+8): wave ig -> element k40+ig (prologue only)
#define STAGEU8(k40)                                                                    \
  {                                                                                     \
    int k4e = (k40) + ig;                                                               \
    const uint4* src = ub + (long long)k4e * 1024 + dl;                                 \
    __builtin_amdgcn_global_load_lds((const GAS void*)src,                              \
                                     (LAS void*)(u_r + (k4e & 31) * 64), 16, 0, 0);     \
  }

  const int i0 = a * 128;
  const int ibase = i0 + ig * 16;
  const int niter = (4 * a + 4) < 16 ? (4 * a + 4) : 16;   // 32-tap chunks

  STAGEU8(16 * a - 8); STAGEU8(16 * a); STAGEU8(16 * a + 8);
  if (ig < 4) {   // stage w chunk 0 (elements 0..3)
    const uint4* src = we4 + (size_t)ig * 1024 + d0 + dl;
    __builtin_amdgcn_global_load_lds((const GAS void*)src,
                                     (LAS void*)(&w_s[0][ig][0]), 16, 0, 0);
  }
  __syncthreads();

  float acc[16];
#pragma unroll
  for (int o = 0; o < 16; ++o) acc[o] = 0.f;

#pragma unroll 1
  for (int c = 0; c < niter; ++c) {
    if (ig < 4) {
      // u elements for chunk c+1: [16a-4c-8, 16a-4c-4)  (disjoint from this chunk's reads)
      int k4e = 16 * a - 4 * c - 8 + ig;
      const uint4* usrc = ub + (long long)k4e * 1024 + dl;
      __builtin_amdgcn_global_load_lds((const GAS void*)usrc,
                                       (LAS void*)(u_r + (k4e & 31) * 64), 16, 0, 0);
      // w elements for chunk c+1: [4(c+1), 4(c+1)+4) into opposite buffer
      const uint4* wsrc = we4 + (size_t)(4 * (c + 1) + ig) * 1024 + d0 + dl;
      __builtin_amdgcn_global_load_lds((const GAS void*)wsrc,
                                       (LAS void*)(&w_s[(c + 1) & 1][ig][0]), 16, 0, 0);
    }
    const int cb = c & 1;
    const int kbase = 16 * a + 2 * ig - 4 * c - 2;
#pragma unroll
    for (int s = 0; s < 2; ++s) {
      const int kb = kbase - 2 * s;
      uint4 v0 = u_r[((kb + 0) & 31) * 64 + dl];
      uint4 v1 = u_r[((kb + 1) & 31) * 64 + dl];
      uint4 v2 = u_r[((kb + 2) & 31) * 64 + dl];
      uint4 v3 = u_r[((kb + 3) & 31) * 64 + dl];
      uint P[16];
      P[0] = v0.x; P[1] = v0.y; P[2] = v0.z; P[3] = v0.w;
      P[4] = v1.x; P[5] = v1.y; P[6] = v1.z; P[7] = v1.w;
      P[8] = v2.x; P[9] = v2.y; P[10] = v2.z; P[11] = v2.w;
      P[12] = v3.x; P[13] = v3.y; P[14] = v3.z; P[15] = v3.w;
      uint4 wv0 = w_s[cb][2 * s][dl];
      uint4 wv1 = w_s[cb][2 * s + 1][dl];
      uint W[8];
      W[0] = wv0.x; W[1] = wv0.y; W[2] = wv0.z; W[3] = wv0.w;
      W[4] = wv1.x; W[5] = wv1.y; W[6] = wv1.z; W[7] = wv1.w;
      uint WS[8];
#pragma unroll
      for (int q = 0; q < 8; ++q) WS[q] = __builtin_amdgcn_alignbit(W[q], W[q], 16);
      uint pe[15];
#pragma unroll
      for (int j = 0; j < 15; ++j) pe[j] = __builtin_amdgcn_perm(P[j + 1], P[j], 0x03020504u);
#pragma unroll
      for (int q = 0; q < 8; ++q) {
#pragma unroll
        for (int h = 0; h < 8; ++h) {
          acc[2 * h]     = dot2(W[q],  pe[7 - q + h], acc[2 * h]);
          acc[2 * h + 1] = dot2(WS[q], P[8 - q + h],  acc[2 * h + 1]);
        }
      }
    }
    __syncthreads();
  }

#pragma unroll
  for (int o = 0; o < 16; ++o)
    out[((size_t)b_ * SEQ + 2 * (ibase + o) + p) * D_MODEL + d0 + dl] = acc[o];
#undef STAGEU8
}

extern "C" void kernel_launch(void* const* d_in, const int* in_sizes, int n_in,
                              void* d_out, int out_size, void* d_ws, size_t ws_size,
                              hipStream_t stream) {
  const float* x   = (const float*)d_in[0];   // [4][2048][1024]
  const float* Mi  = (const float*)d_in[1];   // [1024][1024]
  const float* Mf  = (const float*)d_in[2];   // [24][1024]
  const float* phi = (const float*)d_in[3];   // [2048][24]
  float* out = (float*)d_out;

  // Mt (2MB) lives in d_out -- dead before conv writes out.
  unsigned short* Mt = (unsigned short*)d_out;

  char* ws = (char*)d_ws;
  uint4* we4 = (uint4*)(ws);                   // 72*1024*16B = 1.18 MB
  uint4* u4  = (uint4*)(ws + (2u << 20));      // 8*152*1024*16B = 19.9 MB

  hipLaunchKernelGGL(k_zero_guard, dim3(96, 8), dim3(256), 0, stream, u4);
  hipLaunchKernelGGL(k_transpose_M, dim3(32, 32), dim3(256), 0, stream, Mi, Mt);
  hipLaunchKernelGGL(k_we4, dim3(72, 4), dim3(256), 0, stream, phi, Mf, we4);
  hipLaunchKernelGGL(k_gemm, dim3(512), dim3(256), 0, stream, x, Mt, (uint*)u4);
  hipLaunchKernelGGL(k_conv, dim3(1024), dim3(512), 0, stream, u4, we4, out);
}

// Round 15
// 123.986 us; speedup vs baseline: 1.1239x; 1.1239x over previous
//
#include <hip/hip_runtime.h>
#include <stdint.h>

#define D_MODEL 1024
#define SEQ 2048
#define HALF 1024
#define K_EIG 24
#define GUARD4 24              // zero 16B-elements (8 rows each) before each slice = 192 rows
#define K4 128                 // real elements per slice (1024 rows / 8)
#define K4P (GUARD4 + K4)      // 152
#define WE_JP4 72              // 64 real + 8 zero (stage overrun)

typedef __attribute__((ext_vector_type(8))) short bf16x8;
typedef __attribute__((ext_vector_type(4))) float f32x4;
typedef _Float16 f16;
typedef _Float16 f16x2 __attribute__((ext_vector_type(2)));
typedef unsigned int uint;

#define GAS __attribute__((address_space(1)))
#define LAS __attribute__((address_space(3)))

static __device__ __forceinline__ unsigned short f2bf(float f) {
  union { float f; uint32_t u; } v; v.f = f;
  uint32_t u = v.u;
  u += 0x7FFFu + ((u >> 16) & 1u);
  return (unsigned short)(u >> 16);
}

static __device__ __forceinline__ float dot2(uint w2, uint u2, float c) {
  return __builtin_amdgcn_fdot2(__builtin_bit_cast(f16x2, w2),
                                __builtin_bit_cast(f16x2, u2), c, false);
}

static __device__ __forceinline__ uint pkrtz(float lo, float hi) {
  return __builtin_bit_cast(uint, __builtin_amdgcn_cvt_pkrtz(lo, hi));
}

static __device__ __forceinline__ uint pkbf(float lo, float hi) {
  return (uint)f2bf(lo) | ((uint)f2bf(hi) << 16);
}

// ---------------- zero the per-slice guard elements of u4 ----------------
__global__ void k_zero_guard(uint4* __restrict__ u4) {
  int idx = blockIdx.x * 256 + threadIdx.x;   // grid (96,8): 24576 uint4 per slice guard
  int r = blockIdx.y;
  u4[(size_t)r * (K4P * 1024) + idx] = make_uint4(0u, 0u, 0u, 0u);
}

// ------------- M_inputs [K][N] fp32 -> Mt [N][K] bf16 -------------
__global__ void k_transpose_M(const float* __restrict__ M, unsigned short* __restrict__ Mt) {
  __shared__ float tile[32][33];
  int k0 = blockIdx.y * 32, n0 = blockIdx.x * 32;
  int tx = threadIdx.x & 31, ty = threadIdx.x >> 5;
  #pragma unroll
  for (int r = 0; r < 32; r += 8)
    tile[ty + r][tx] = M[(size_t)(k0 + ty + r) * D_MODEL + n0 + tx];
  __syncthreads();
  #pragma unroll
  for (int r = 0; r < 32; r += 8)
    Mt[(size_t)(n0 + ty + r) * D_MODEL + k0 + tx] = f2bf(tile[tx][ty + r]);
}

// ------------- we4[jp4][d] = 16B of 8 even-taps: dword q = (w_e[8jp4+2q], w_e[8jp4+2q+1]) f16 -------------
__global__ __launch_bounds__(256) void k_we4(const float* __restrict__ phi,
                                             const float* __restrict__ Mf,
                                             uint4* __restrict__ we4) {
  const int jp4 = blockIdx.x;                       // 0..71
  const int d = blockIdx.y * 256 + threadIdx.x;     // 0..1023
  if (jp4 >= 64) {
    we4[(size_t)jp4 * D_MODEL + d] = make_uint4(0u, 0u, 0u, 0u);
    return;
  }
  __shared__ float ph[8][K_EIG];
  if (threadIdx.x < 8 * K_EIG) {
    int s = threadIdx.x / K_EIG, k = threadIdx.x - s * K_EIG;
    ph[s][k] = phi[(size_t)(16 * jp4 + 2 * s) * K_EIG + k];
  }
  __syncthreads();
  float s[8] = {};
  #pragma unroll
  for (int k = 0; k < K_EIG; ++k) {
    float mv = Mf[(size_t)k * D_MODEL + d];
    #pragma unroll
    for (int j = 0; j < 8; ++j) s[j] = fmaf(ph[j][k], mv, s[j]);
  }
  uint4 o;
  o.x = pkrtz(2.f * s[0], 2.f * s[1]);
  o.y = pkrtz(2.f * s[2], 2.f * s[3]);
  o.z = pkrtz(2.f * s[4], 2.f * s[5]);
  o.w = pkrtz(2.f * s[6], 2.f * s[7]);
  we4[(size_t)jp4 * D_MODEL + d] = o;
}

// ------------- u = x @ M (bf16 MFMA, B^T), A staged fp32 via global_load_lds, XOR-swizzled -------------
// A LDS: float[128][32], 16B chunk c of row r stored at pos c ^ (r&7) (2-way reads = free).
// B LDS: ushort[128][32], 16B chunk c of row n stored at pos c ^ (n&3) (4-way reads).
// Swizzle applied via pre-swizzled per-lane GLOBAL source; LDS dest stays linear (rule #21).
__global__ __launch_bounds__(256) void k_gemm(const float* __restrict__ X,
                                              const unsigned short* __restrict__ Bt,
                                              uint* __restrict__ Ug) {
  __shared__ float Asf[128 * 32];           // 16KB
  __shared__ unsigned short Bs[128 * 32];   // 8KB
  const int bid = (int)blockIdx.x;             // 0..511
  const int swz = (bid & 7) * 64 + (bid >> 3); // XCD swizzle
  const int m0 = (swz >> 3) * 128;
  const int n0 = (swz & 7) * 128;
  const int tid = threadIdx.x;
  const int lane = tid & 63;
  const int wave = tid >> 6;
  const int wm = wave >> 1, wn = wave & 1;
  const int qo = lane >> 4;

  // A staging: 4 insts/wave, 8 rows each; lane covers row rbase+(lane>>3), LDS pos lane&7.
  const int a_row = lane >> 3;
  const int a_chunk = (lane & 7) ^ a_row;      // source chunk (floats a_chunk*4..+3)
  // B staging: 2 insts/wave, 16 rows each; lane covers row rbase+(lane>>2), pos lane&3.
  const int b_row = lane >> 2;
  const int b_chunk = (lane & 3) ^ (b_row & 3);   // source chunk (bf16 b_chunk*8..+7)

  f32x4 acc[4][4] = {};

  for (int k0 = 0; k0 < 1024; k0 += 32) {
    __syncthreads();
    #pragma unroll
    for (int c = 0; c < 4; ++c) {
      int rbase = wave * 32 + c * 8;
      const float* src = X + (size_t)(m0 + rbase + a_row) * 1024 + k0 + a_chunk * 4;
      __builtin_amdgcn_global_load_lds((const GAS void*)src, (LAS void*)(Asf + rbase * 32), 16, 0, 0);
    }
    #pragma unroll
    for (int c = 0; c < 2; ++c) {
      int rbase = wave * 32 + c * 16;
      const unsigned short* src = Bt + (size_t)(n0 + rbase + b_row) * 1024 + k0 + b_chunk * 8;
      __builtin_amdgcn_global_load_lds((const GAS void*)src, (LAS void*)(Bs + rbase * 32), 16, 0, 0);
    }
    __syncthreads();

    bf16x8 a[4], b[4];
    #pragma unroll
    for (int mt = 0; mt < 4; ++mt) {
      int m = wm * 64 + mt * 16 + (lane & 15);
      const float* base = Asf + m * 32;
      int s0 = (2 * qo) ^ (lane & 7);         // slot of chunk 2qo (floats 8qo..8qo+3)
      int s1 = s0 ^ 1;                        // slot of chunk 2qo+1
      float4 f0 = *(const float4*)(base + s0 * 4);
      float4 f1 = *(const float4*)(base + s1 * 4);
      uint4 pk;
      pk.x = pkbf(f0.x, f0.y); pk.y = pkbf(f0.z, f0.w);
      pk.z = pkbf(f1.x, f1.y); pk.w = pkbf(f1.z, f1.w);
      a[mt] = __builtin_bit_cast(bf16x8, pk);
    }
    #pragma unroll
    for (int nt = 0; nt < 4; ++nt) {
      int n = wn * 64 + nt * 16 + (lane & 15);
      int sb = qo ^ (lane & 3);               // slot of chunk qo
      b[nt] = *(const bf16x8*)(Bs + n * 32 + sb * 8);
    }
    #pragma unroll
    for (int mt = 0; mt < 4; ++mt)
      #pragma unroll
      for (int nt = 0; nt < 4; ++nt)
        acc[mt][nt] = __builtin_amdgcn_mfma_f32_16x16x32_bf16(a[mt], b[nt], acc[mt][nt], 0, 0, 0);
  }

  // epilogue: quad q -> t = t0+q. q0,q2 -> slice r_e rows i,i+1; q1,q3 -> r_o.
  const int crow = (lane >> 4) * 4;
  const int ccol = lane & 15;
  #pragma unroll
  for (int mt = 0; mt < 4; ++mt) {
    int m = m0 + wm * 64 + mt * 16 + crow;
    int b_ = m >> 11;
    int t0 = m & 2047;
    int r_e = b_ << 1;
    int k4 = t0 >> 4;
    int dwo = (t0 >> 2) & 3;
    size_t base_e = ((size_t)(r_e * K4P + GUARD4 + k4) * 1024) * 4 + dwo;
    size_t base_o = ((size_t)((r_e + 1) * K4P + GUARD4 + k4) * 1024) * 4 + dwo;
    #pragma unroll
    for (int nt = 0; nt < 4; ++nt) {
      int n = n0 + wn * 64 + nt * 16 + ccol;
      Ug[base_e + (size_t)n * 4] = pkrtz(acc[mt][nt][0], acc[mt][nt][2]);
      Ug[base_o + (size_t)n * 4] = pkrtz(acc[mt][nt][1], acc[mt][nt][3]);
    }
  }
}

// ------------- depthwise causal conv: packed-pair ring + dot2, one tile per block (R12 proven) -------------
__global__ __launch_bounds__(512, 6) void k_conv(const uint4* __restrict__ u4,
                                                 const uint4* __restrict__ we4,
                                                 float* __restrict__ out) {
  __shared__ uint4 u_r[32 * 64];     // 32KB ring: [k4 & 31][dl], element = 4 pairs = 8 rows
  __shared__ uint4 w_s[2][8][64];    // 16KB: double-buffered chunk of 8 w-elements
  const int flat = blockIdx.x;       // 0..1023
  const int dt = flat & 15;          // flat&7 pins d-column to one XCD
  const int r  = (flat >> 4) & 7;
  const int a  = 7 - (flat >> 7);    // heavy tiles dispatched first
  const int d0 = dt * 64;
  const int tid = threadIdx.x;
  const int dl = tid & 63;
  const int ig = tid >> 6;           // wave 0..7

  const uint4* ub = u4 + ((size_t)r * K4P + GUARD4) * 1024 + d0;   // + k4*1024 + dl
  const int b_ = r >> 1, p = r & 1;

#define STAGEU(k40)                                                                     \
  {                                                                                     \
    int k4e = (k40) + ig;                                                               \
    const uint4* src = ub + (long long)k4e * 1024 + dl;                                 \
    __builtin_amdgcn_global_load_lds((const GAS void*)src,                              \
                                     (LAS void*)(u_r + (k4e & 31) * 64), 16, 0, 0);     \
  }

#define STAGEW(ch)                                                                      \
  {                                                                                     \
    const uint4* src = we4 + (size_t)((ch) * 8 + ig) * 1024 + d0 + dl;                  \
    __builtin_amdgcn_global_load_lds((const GAS void*)src,                              \
                                     (LAS void*)(&w_s[(ch) & 1][ig][0]), 16, 0, 0);     \
  }

  const int i0 = a * 128;
  const int ibase = i0 + ig * 16;
  const int niter = (2 * a + 2) < 8 ? (2 * a + 2) : 8;   // zero-tap chunks skipped

  STAGEU(16 * a - 8); STAGEU(16 * a); STAGEU(16 * a + 8);
  STAGEW(0);
  __syncthreads();

  float acc[16];
#pragma unroll
  for (int o = 0; o < 16; ++o) acc[o] = 0.f;

#pragma unroll 1
  for (int c = 0; c < niter; ++c) {
    STAGEU(16 * a - 8 * c - 16);          // elements for chunk c+1 (disjoint slots)
    STAGEW(c + 1);                        // w for chunk c+1 (opposite buffer)
    const int cb = c & 1;
    const int kbase = 16 * a + 2 * ig - 8 * c - 2;
#pragma unroll
    for (int s = 0; s < 4; ++s) {
      const int kb = kbase - 2 * s;
      uint4 v0 = u_r[((kb + 0) & 31) * 64 + dl];
      uint4 v1 = u_r[((kb + 1) & 31) * 64 + dl];
      uint4 v2 = u_r[((kb + 2) & 31) * 64 + dl];
      uint4 v3 = u_r[((kb + 3) & 31) * 64 + dl];
      uint P[16];
      P[0] = v0.x; P[1] = v0.y; P[2] = v0.z; P[3] = v0.w;
      P[4] = v1.x; P[5] = v1.y; P[6] = v1.z; P[7] = v1.w;
      P[8] = v2.x; P[9] = v2.y; P[10] = v2.z; P[11] = v2.w;
      P[12] = v3.x; P[13] = v3.y; P[14] = v3.z; P[15] = v3.w;
      uint4 wv0 = w_s[cb][2 * s][dl];
      uint4 wv1 = w_s[cb][2 * s + 1][dl];
      uint W[8];
      W[0] = wv0.x; W[1] = wv0.y; W[2] = wv0.z; W[3] = wv0.w;
      W[4] = wv1.x; W[5] = wv1.y; W[6] = wv1.z; W[7] = wv1.w;
      uint WS[8];
#pragma unroll
      for (int q = 0; q < 8; ++q) WS[q] = __builtin_amdgcn_alignbit(W[q], W[q], 16);
      uint pe[15];
#pragma unroll
      for (int j = 0; j < 15; ++j) pe[j] = __builtin_amdgcn_perm(P[j + 1], P[j], 0x03020504u);
#pragma unroll
      for (int q = 0; q < 8; ++q) {
#pragma unroll
        for (int h = 0; h < 8; ++h) {
          acc[2 * h]     = dot2(W[q],  pe[7 - q + h], acc[2 * h]);
          acc[2 * h + 1] = dot2(WS[q], P[8 - q + h],  acc[2 * h + 1]);
        }
      }
    }
    __syncthreads();
  }

#pragma unroll
  for (int o = 0; o < 16; ++o)
    out[((size_t)b_ * SEQ + 2 * (ibase + o) + p) * D_MODEL + d0 + dl] = acc[o];
#undef STAGEU
#undef STAGEW
}

extern "C" void kernel_launch(void* const* d_in, const int* in_sizes, int n_in,
                              void* d_out, int out_size, void* d_ws, size_t ws_size,
                              hipStream_t stream) {
  const float* x   = (const float*)d_in[0];   // [4][2048][1024]
  const float* Mi  = (const float*)d_in[1];   // [1024][1024]
  const float* Mf  = (const float*)d_in[2];   // [24][1024]
  const float* phi = (const float*)d_in[3];   // [2048][24]
  float* out = (float*)d_out;

  // Mt (2MB) lives in d_out -- dead before conv writes out.
  unsigned short* Mt = (unsigned short*)d_out;

  char* ws = (char*)d_ws;
  uint4* we4 = (uint4*)(ws);                   // 72*1024*16B = 1.18 MB
  uint4* u4  = (uint4*)(ws + (2u << 20));      // 8*152*1024*16B = 19.9 MB

  hipLaunchKernelGGL(k_zero_guard, dim3(96, 8), dim3(256), 0, stream, u4);
  hipLaunchKernelGGL(k_transpose_M, dim3(32, 32), dim3(256), 0, stream, Mi, Mt);
  hipLaunchKernelGGL(k_we4, dim3(72, 4), dim3(256), 0, stream, phi, Mf, we4);
  hipLaunchKernelGGL(k_gemm, dim3(512), dim3(256), 0, stream, x, Mt, (uint*)u4);
  hipLaunchKernelGGL(k_conv, dim3(1024), dim3(512), 0, stream, u4, we4, out);
}

// Round 16
// 117.556 us; speedup vs baseline: 1.1854x; 1.0547x over previous
//
#include <hip/hip_runtime.h>
#include <stdint.h>

#define D_MODEL 1024
#define SEQ 2048
#define HALF 1024
#define K_EIG 24
#define GUARD4 24              // zero 16B-elements (8 rows each) before each slice = 192 rows
#define K4 128                 // real elements per slice (1024 rows / 8)
#define K4P (GUARD4 + K4)      // 152
#define WE_JP4 72              // 64 real + 8 zero (stage overrun)

typedef __attribute__((ext_vector_type(8))) short bf16x8;
typedef __attribute__((ext_vector_type(4))) float f32x4;
typedef _Float16 f16;
typedef _Float16 f16x2 __attribute__((ext_vector_type(2)));
typedef unsigned int uint;

#define GAS __attribute__((address_space(1)))
#define LAS __attribute__((address_space(3)))

static __device__ __forceinline__ unsigned short f2bf(float f) {
  union { float f; uint32_t u; } v; v.f = f;
  uint32_t u = v.u;
  u += 0x7FFFu + ((u >> 16) & 1u);
  return (unsigned short)(u >> 16);
}

static __device__ __forceinline__ float dot2(uint w2, uint u2, float c) {
  return __builtin_amdgcn_fdot2(__builtin_bit_cast(f16x2, w2),
                                __builtin_bit_cast(f16x2, u2), c, false);
}

static __device__ __forceinline__ uint pkrtz(float lo, float hi) {
  return __builtin_bit_cast(uint, __builtin_amdgcn_cvt_pkrtz(lo, hi));
}

static __device__ __forceinline__ uint pkbf(float lo, float hi) {
  return (uint)f2bf(lo) | ((uint)f2bf(hi) << 16);
}

// ------------- merged prep: [0,768) zero_guard | [768,1792) transpose_M | [1792,2080) we4 -------------
__global__ __launch_bounds__(256) void k_prep(const float* __restrict__ Mi,
                                              const float* __restrict__ phi,
                                              const float* __restrict__ Mf,
                                              uint4* __restrict__ u4,
                                              unsigned short* __restrict__ Mt,
                                              uint4* __restrict__ we4) {
  __shared__ float smem[1056];
  const int blk = (int)blockIdx.x;
  const int tidx = threadIdx.x;

  if (blk < 768) {
    // zero guard: 8 slices x 24576 uint4; 96 blocks per slice
    int r = blk / 96;
    int idx = (blk - r * 96) * 256 + tidx;
    u4[(size_t)r * (K4P * 1024) + idx] = make_uint4(0u, 0u, 0u, 0u);
    return;
  }
  if (blk < 1792) {
    // transpose M: 1024 blocks of 32x32 tile
    int bidx = blk - 768;
    int n0 = (bidx & 31) * 32, k0 = (bidx >> 5) * 32;
    float (*tile)[33] = (float(*)[33])smem;
    int tx = tidx & 31, ty = tidx >> 5;
    #pragma unroll
    for (int r = 0; r < 32; r += 8)
      tile[ty + r][tx] = Mi[(size_t)(k0 + ty + r) * D_MODEL + n0 + tx];
    __syncthreads();
    #pragma unroll
    for (int r = 0; r < 32; r += 8)
      Mt[(size_t)(n0 + ty + r) * D_MODEL + k0 + tx] = f2bf(tile[tx][ty + r]);
    return;
  }
  // we4: 288 blocks = 72 jp4 x 4 d-tiles
  {
    int bidx = blk - 1792;
    int jp4 = bidx % 72;
    int d = (bidx / 72) * 256 + tidx;
    if (jp4 >= 64) {
      we4[(size_t)jp4 * D_MODEL + d] = make_uint4(0u, 0u, 0u, 0u);
      return;
    }
    float (*ph)[K_EIG] = (float(*)[K_EIG])smem;
    if (tidx < 8 * K_EIG) {
      int s = tidx / K_EIG, k = tidx - s * K_EIG;
      ph[s][k] = phi[(size_t)(16 * jp4 + 2 * s) * K_EIG + k];
    }
    __syncthreads();
    float s[8] = {};
    #pragma unroll
    for (int k = 0; k < K_EIG; ++k) {
      float mv = Mf[(size_t)k * D_MODEL + d];
      #pragma unroll
      for (int j = 0; j < 8; ++j) s[j] = fmaf(ph[j][k], mv, s[j]);
    }
    uint4 o;
    o.x = pkrtz(2.f * s[0], 2.f * s[1]);
    o.y = pkrtz(2.f * s[2], 2.f * s[3]);
    o.z = pkrtz(2.f * s[4], 2.f * s[5]);
    o.w = pkrtz(2.f * s[6], 2.f * s[7]);
    we4[(size_t)jp4 * D_MODEL + d] = o;
  }
}

// ------------- u = x @ M (bf16 MFMA, B^T), fp32-A via global_load_lds, XOR-swizzled, double-buffered -------------
// A LDS: float[128][32] x2, chunk c of row r at pos c ^ (r&7). B: ushort[128][32] x2, pos c ^ (n&3).
// One barrier per K-step: stage(t+1) issued BEFORE compute(t), drain covered by compute.
__global__ __launch_bounds__(256) void k_gemm(const float* __restrict__ X,
                                              const unsigned short* __restrict__ Bt,
                                              uint* __restrict__ Ug) {
  __shared__ float Asf[2][128 * 32];           // 2 x 16KB
  __shared__ unsigned short Bs[2][128 * 32];   // 2 x 8KB
  const int bid = (int)blockIdx.x;             // 0..511
  const int swz = (bid & 7) * 64 + (bid >> 3); // XCD swizzle
  const int m0 = (swz >> 3) * 128;
  const int n0 = (swz & 7) * 128;
  const int tid = threadIdx.x;
  const int lane = tid & 63;
  const int wave = tid >> 6;
  const int wm = wave >> 1, wn = wave & 1;
  const int qo = lane >> 4;

  const int a_row = lane >> 3;
  const int a_chunk = (lane & 7) ^ a_row;         // A source chunk (floats a_chunk*4..+3)
  const int b_row = lane >> 2;
  const int b_chunk = (lane & 3) ^ (b_row & 3);   // B source chunk (bf16 b_chunk*8..+7)

#define GSTAGE(buf, k0v)                                                                  \
  {                                                                                       \
    _Pragma("unroll") for (int c = 0; c < 4; ++c) {                                       \
      int rbase = wave * 32 + c * 8;                                                      \
      const float* srcA = X + (size_t)(m0 + rbase + a_row) * 1024 + (k0v) + a_chunk * 4;  \
      __builtin_amdgcn_global_load_lds((const GAS void*)srcA,                             \
                                       (LAS void*)(Asf[buf] + rbase * 32), 16, 0, 0);     \
    }                                                                                     \
    _Pragma("unroll") for (int c = 0; c < 2; ++c) {                                       \
      int rbase = wave * 32 + c * 16;                                                     \
      const unsigned short* srcB = Bt + (size_t)(n0 + rbase + b_row) * 1024 + (k0v) + b_chunk * 8; \
      __builtin_amdgcn_global_load_lds((const GAS void*)srcB,                             \
                                       (LAS void*)(Bs[buf] + rbase * 32), 16, 0, 0);      \
    }                                                                                     \
  }

  f32x4 acc[4][4] = {};

  GSTAGE(0, 0);
  __syncthreads();

#pragma unroll 1
  for (int t = 0; t < 32; ++t) {
    const int cur = t & 1;
    if (t < 31) GSTAGE(cur ^ 1, (t + 1) * 32);

    bf16x8 a[4], b[4];
    #pragma unroll
    for (int mt = 0; mt < 4; ++mt) {
      int m = wm * 64 + mt * 16 + (lane & 15);
      const float* base = Asf[cur] + m * 32;
      int s0 = (2 * qo) ^ (lane & 7);
      int s1 = s0 ^ 1;
      float4 f0 = *(const float4*)(base + s0 * 4);
      float4 f1 = *(const float4*)(base + s1 * 4);
      uint4 pk;
      pk.x = pkbf(f0.x, f0.y); pk.y = pkbf(f0.z, f0.w);
      pk.z = pkbf(f1.x, f1.y); pk.w = pkbf(f1.z, f1.w);
      a[mt] = __builtin_bit_cast(bf16x8, pk);
    }
    #pragma unroll
    for (int nt = 0; nt < 4; ++nt) {
      int n = wn * 64 + nt * 16 + (lane & 15);
      int sb = qo ^ (lane & 3);
      b[nt] = *(const bf16x8*)(Bs[cur] + n * 32 + sb * 8);
    }
    #pragma unroll
    for (int mt = 0; mt < 4; ++mt)
      #pragma unroll
      for (int nt = 0; nt < 4; ++nt)
        acc[mt][nt] = __builtin_amdgcn_mfma_f32_16x16x32_bf16(a[mt], b[nt], acc[mt][nt], 0, 0, 0);

    __syncthreads();   // drains stage(t+1) (covered by compute) + WAR protection
  }
#undef GSTAGE

  // epilogue: quad q -> t = t0+q. q0,q2 -> slice r_e rows i,i+1; q1,q3 -> r_o.
  const int crow = (lane >> 4) * 4;
  const int ccol = lane & 15;
  #pragma unroll
  for (int mt = 0; mt < 4; ++mt) {
    int m = m0 + wm * 64 + mt * 16 + crow;
    int b_ = m >> 11;
    int t0 = m & 2047;
    int r_e = b_ << 1;
    int k4 = t0 >> 4;
    int dwo = (t0 >> 2) & 3;
    size_t base_e = ((size_t)(r_e * K4P + GUARD4 + k4) * 1024) * 4 + dwo;
    size_t base_o = ((size_t)((r_e + 1) * K4P + GUARD4 + k4) * 1024) * 4 + dwo;
    #pragma unroll
    for (int nt = 0; nt < 4; ++nt) {
      int n = n0 + wn * 64 + nt * 16 + ccol;
      Ug[base_e + (size_t)n * 4] = pkrtz(acc[mt][nt][0], acc[mt][nt][2]);
      Ug[base_o + (size_t)n * 4] = pkrtz(acc[mt][nt][1], acc[mt][nt][3]);
    }
  }
}

// ------------- depthwise causal conv: packed-pair ring + dot2, one tile per block (R12/R15 proven) -------------
__global__ __launch_bounds__(512, 6) void k_conv(const uint4* __restrict__ u4,
                                                 const uint4* __restrict__ we4,
                                                 float* __restrict__ out) {
  __shared__ uint4 u_r[32 * 64];     // 32KB ring: [k4 & 31][dl], element = 4 pairs = 8 rows
  __shared__ uint4 w_s[2][8][64];    // 16KB: double-buffered chunk of 8 w-elements
  const int flat = blockIdx.x;       // 0..1023
  const int dt = flat & 15;          // flat&7 pins d-column to one XCD
  const int r  = (flat >> 4) & 7;
  const int a  = 7 - (flat >> 7);    // heavy tiles dispatched first
  const int d0 = dt * 64;
  const int tid = threadIdx.x;
  const int dl = tid & 63;
  const int ig = tid >> 6;           // wave 0..7

  const uint4* ub = u4 + ((size_t)r * K4P + GUARD4) * 1024 + d0;   // + k4*1024 + dl
  const int b_ = r >> 1, p = r & 1;

#define STAGEU(k40)                                                                     \
  {                                                                                     \
    int k4e = (k40) + ig;                                                               \
    const uint4* src = ub + (long long)k4e * 1024 + dl;                                 \
    __builtin_amdgcn_global_load_lds((const GAS void*)src,                              \
                                     (LAS void*)(u_r + (k4e & 31) * 64), 16, 0, 0);     \
  }

#define STAGEW(ch)                                                                      \
  {                                                                                     \
    const uint4* src = we4 + (size_t)((ch) * 8 + ig) * 1024 + d0 + dl;                  \
    __builtin_amdgcn_global_load_lds((const GAS void*)src,                              \
                                     (LAS void*)(&w_s[(ch) & 1][ig][0]), 16, 0, 0);     \
  }

  const int i0 = a * 128;
  const int ibase = i0 + ig * 16;
  const int niter = (2 * a + 2) < 8 ? (2 * a + 2) : 8;   // zero-tap chunks skipped

  STAGEU(16 * a - 8); STAGEU(16 * a); STAGEU(16 * a + 8);
  STAGEW(0);
  __syncthreads();

  float acc[16];
#pragma unroll
  for (int o = 0; o < 16; ++o) acc[o] = 0.f;

#pragma unroll 1
  for (int c = 0; c < niter; ++c) {
    STAGEU(16 * a - 8 * c - 16);          // elements for chunk c+1 (disjoint slots)
    STAGEW(c + 1);                        // w for chunk c+1 (opposite buffer)
    const int cb = c & 1;
    const int kbase = 16 * a + 2 * ig - 8 * c - 2;
#pragma unroll
    for (int s = 0; s < 4; ++s) {
      const int kb = kbase - 2 * s;
      uint4 v0 = u_r[((kb + 0) & 31) * 64 + dl];
      uint4 v1 = u_r[((kb + 1) & 31) * 64 + dl];
      uint4 v2 = u_r[((kb + 2) & 31) * 64 + dl];
      uint4 v3 = u_r[((kb + 3) & 31) * 64 + dl];
      uint P[16];
      P[0] = v0.x; P[1] = v0.y; P[2] = v0.z; P[3] = v0.w;
      P[4] = v1.x; P[5] = v1.y; P[6] = v1.z; P[7] = v1.w;
      P[8] = v2.x; P[9] = v2.y; P[10] = v2.z; P[11] = v2.w;
      P[12] = v3.x; P[13] = v3.y; P[14] = v3.z; P[15] = v3.w;
      uint4 wv0 = w_s[cb][2 * s][dl];
      uint4 wv1 = w_s[cb][2 * s + 1][dl];
      uint W[8];
      W[0] = wv0.x; W[1] = wv0.y; W[2] = wv0.z; W[3] = wv0.w;
      W[4] = wv1.x; W[5] = wv1.y; W[6] = wv1.z; W[7] = wv1.w;
      uint WS[8];
#pragma unroll
      for (int q = 0; q < 8; ++q) WS[q] = __builtin_amdgcn_alignbit(W[q], W[q], 16);
      uint pe[15];
#pragma unroll
      for (int j = 0; j < 15; ++j) pe[j] = __builtin_amdgcn_perm(P[j + 1], P[j], 0x03020504u);
#pragma unroll
      for (int q = 0; q < 8; ++q) {
#pragma unroll
        for (int h = 0; h < 8; ++h) {
          acc[2 * h]     = dot2(W[q],  pe[7 - q + h], acc[2 * h]);
          acc[2 * h + 1] = dot2(WS[q], P[8 - q + h],  acc[2 * h + 1]);
        }
      }
    }
    __syncthreads();
  }

#pragma unroll
  for (int o = 0; o < 16; ++o)
    out[((size_t)b_ * SEQ + 2 * (ibase + o) + p) * D_MODEL + d0 + dl] = acc[o];
#undef STAGEU
#undef STAGEW
}

extern "C" void kernel_launch(void* const* d_in, const int* in_sizes, int n_in,
                              void* d_out, int out_size, void* d_ws, size_t ws_size,
                              hipStream_t stream) {
  const float* x   = (const float*)d_in[0];   // [4][2048][1024]
  const float* Mi  = (const float*)d_in[1];   // [1024][1024]
  const float* Mf  = (const float*)d_in[2];   // [24][1024]
  const float* phi = (const float*)d_in[3];   // [2048][24]
  float* out = (float*)d_out;

  // Mt (2MB) lives in d_out -- dead before conv writes out.
  unsigned short* Mt = (unsigned short*)d_out;

  char* ws = (char*)d_ws;
  uint4* we4 = (uint4*)(ws);                   // 72*1024*16B = 1.18 MB
  uint4* u4  = (uint4*)(ws + (2u << 20));      // 8*152*1024*16B = 19.9 MB

  hipLaunchKernelGGL(k_prep, dim3(2080), dim3(256), 0, stream, Mi, phi, Mf, u4, Mt, we4);
  hipLaunchKernelGGL(k_gemm, dim3(512), dim3(256), 0, stream, x, Mt, (uint*)u4);
  hipLaunchKernelGGL(k_conv, dim3(1024), dim3(512), 0, stream, u4, we4, out);
}